// Round 12
// baseline (512.436 us; speedup 1.0000x reference)
//
#include <hip/hip_runtime.h>
#include <hip/hip_bf16.h>
#include <stdint.h>

typedef unsigned short u16;
typedef __bf16 bf16x8 __attribute__((ext_vector_type(8)));
typedef float f32x4 __attribute__((ext_vector_type(4)));

// B=4, L=1024, A=8, D=1024, H=16, DK=64
#define MROWS 32768   // B*L*A
#define NDIM  1024
#define KDIM  1024

__device__ __forceinline__ void gload_lds16(const void* g, void* l) {
  __builtin_amdgcn_global_load_lds(
      (__attribute__((address_space(1))) const void*)g,
      (__attribute__((address_space(3))) void*)l,
      16, 0, 0);
}

struct CvtArgs { const float* s[4]; u16* d[4]; };

// weights fp32 -> bf16 (4 x 1M elems; 512 blocks per matrix)
__global__ __launch_bounds__(256) void cvt4_kernel(CvtArgs ca) {
  const int which = blockIdx.x >> 9;
  const float* s = ca.s[which];
  u16* d = ca.d[which];
  const int i = ((((int)blockIdx.x & 511) * 256) + (int)threadIdx.x) * 8;
  const float4 f0 = *(const float4*)(s + i);
  const float4 f1 = *(const float4*)(s + i + 4);
  bf16x8 h;
  h[0] = (__bf16)f0.x; h[1] = (__bf16)f0.y; h[2] = (__bf16)f0.z; h[3] = (__bf16)f0.w;
  h[4] = (__bf16)f1.x; h[5] = (__bf16)f1.y; h[6] = (__bf16)f1.z; h[7] = (__bf16)f1.w;
  *(bf16x8*)((void*)(d + i)) = h;
}

#define SBAR0() __builtin_amdgcn_sched_barrier(0)
#define VM6() asm volatile("s_waitcnt vmcnt(6)" ::: "memory")

// ---------------------------------------------------------------------------
// gemm8f: C[m,n] = sum_k A_f32[m,k]*B_bf16[n,k] + bias[n], C bf16.
// 256x256 tile, BK=32, 512 thr (8 waves 2Mx4N), 32 K-tiles, dbuf LDS 96KB
// (A fp32 2x32KB, B bf16 2x16KB). One phase per tile:
//   { latch ALL frags (16 f32x4 A-reads + cvt->bf16, 4 B-reads);
//     lgkmcnt(0); barrier;            <- slot reads chip-wide complete
//     issue tile t+2 stages (6 gload_lds into THIS buf - now legal);
//     setprio(1); 32 MFMA; setprio(0);
//     vmcnt(6); barrier }             <- tile t+1 landed, t+2 in flight
// Prefetch distance 2 (~2 phases > HBM latency), counted vmcnt never 0
// in-loop. Tail clamps stage tile to 31 (ledger exact; garbage restage into
// a dead/just-read buffer is harmless). Swizzles (both sides, involutions):
//   A fp32 [256][32f]: 8 chunks/row, phys = ch ^ (row&7) -> frag reads
//     conflict-free per 8-lane group.  B bf16 [256][32h]: 4 chunks/row,
//     phys = ch ^ (row&3) -> 2-way max (free).
// ---------------------------------------------------------------------------
__global__ __launch_bounds__(512, 2) void gemm8f(const float* __restrict__ Af,
                                                 const u16* __restrict__ Bw,
                                                 const float* __restrict__ bias,
                                                 u16* __restrict__ Cv,
                                                 int byPerXcd) {
  __shared__ __align__(16) unsigned char As[2][32768];
  __shared__ __align__(16) unsigned char Bs[2][16384];

  const int bid = (int)blockIdx.x;
  const int xcd = bid & 7;
  const int within = bid >> 3;
  const int by = xcd * byPerXcd + (within >> 2);
  const int bx = within & 3;

  const int t = (int)threadIdx.x;
  const int lane = t & 63;
  const int wid = t >> 6;
  const int wm = wid >> 2;        // 0..1 (M half)
  const int wn = wid & 3;         // 0..3 (N quarter)
  const int fr = lane & 15;
  const int hi = lane >> 4;

  // staging descriptors (pre-swizzled source, linear LDS dest)
  size_t aG[4]; int aL[4];
#pragma unroll
  for (int i = 0; i < 4; ++i) {
    const int idx = i * 512 + t;
    const int r = idx >> 3, ch = idx & 7;
    aG[i] = (size_t)r * KDIM + (size_t)((ch ^ (r & 7)) << 2);   // float units
    aL[i] = (i * 512 + (t & ~63)) * 16;
  }
  size_t bG[2]; int bL[2];
#pragma unroll
  for (int i = 0; i < 2; ++i) {
    const int idx = i * 512 + t;
    const int r = idx >> 2, ch = idx & 3;
    bG[i] = (size_t)r * KDIM + (size_t)((ch ^ (r & 3)) << 3);   // u16 units
    bL[i] = (i * 512 + (t & ~63)) * 16;
  }
  const float* Abase = Af + (size_t)(by * 256) * KDIM;
  const u16* Bbase = Bw + (size_t)(bx * 256) * KDIM;

  auto SA = [&](int tile, int d) {
    const float* s = Abase + tile * 32;
#pragma unroll
    for (int i = 0; i < 4; ++i) gload_lds16(s + aG[i], &As[d][aL[i]]);
  };
  auto SB = [&](int tile, int d) {
    const u16* s = Bbase + tile * 32;
#pragma unroll
    for (int i = 0; i < 2; ++i) gload_lds16(s + bG[i], &Bs[d][bL[i]]);
  };

  // fragment read offsets
  int aOffF[8][2];
#pragma unroll
  for (int m = 0; m < 8; ++m)
#pragma unroll
    for (int c = 0; c < 2; ++c)
      aOffF[m][c] = (wm * 128 + m * 16 + fr) * 128 + (((hi * 2 + c) ^ (fr & 7)) << 4);
  int bOffF[4];
#pragma unroll
  for (int n = 0; n < 4; ++n)
    bOffF[n] = (wn * 64 + n * 16 + fr) * 64 + ((hi ^ (fr & 3)) << 4);

  f32x4 acc[8][4] = {};

  // PROLOGUE: stage tiles 0,1; wait tile0 (6 of 12 -> counted).
  SA(0, 0); SB(0, 0); SA(1, 1); SB(1, 1);
  VM6(); SBAR0();
  __builtin_amdgcn_s_barrier();

  for (int kt = 0; kt < 32; ++kt) {
    const int d = kt & 1;

    // latch all fragments (reads of buf d) + cvt A to bf16
    bf16x8 a8[8], b4[4];
#pragma unroll
    for (int m = 0; m < 8; ++m) {
      const f32x4 x0 = *(const f32x4*)((const void*)(As[d] + aOffF[m][0]));
      const f32x4 x1 = *(const f32x4*)((const void*)(As[d] + aOffF[m][1]));
      bf16x8 h;
      h[0] = (__bf16)x0[0]; h[1] = (__bf16)x0[1]; h[2] = (__bf16)x0[2]; h[3] = (__bf16)x0[3];
      h[4] = (__bf16)x1[0]; h[5] = (__bf16)x1[1]; h[6] = (__bf16)x1[2]; h[7] = (__bf16)x1[3];
      a8[m] = h;
    }
#pragma unroll
    for (int n = 0; n < 4; ++n)
      b4[n] = *(const bf16x8*)((const void*)(Bs[d] + bOffF[n]));

    asm volatile("s_waitcnt lgkmcnt(0)" ::: "memory");   // own reads done
    SBAR0();
    __builtin_amdgcn_s_barrier();                        // ALL waves' reads done
    SBAR0();

    // stage tile kt+2 into buf d (reads complete chip-wide; clamped tail
    // restage is a harmless write to a dead/finished buffer).
    const int tn = (kt + 2 < 32) ? kt + 2 : 31;
    SA(tn, d); SB(tn, d);

    __builtin_amdgcn_s_setprio(1);
#pragma unroll
    for (int m = 0; m < 8; ++m)
#pragma unroll
      for (int n = 0; n < 4; ++n)
        acc[m][n] = __builtin_amdgcn_mfma_f32_16x16x32_bf16(a8[m], b4[n], acc[m][n], 0, 0, 0);
    __builtin_amdgcn_s_setprio(0);

    VM6();                                               // tile kt+1 landed
    SBAR0();
    __builtin_amdgcn_s_barrier();
  }

  // epilogue: D col = fr (N), row = hi*4 + jj (M); C bf16 + bias
  const int row0 = by * 256 + wm * 128 + hi * 4;
  const int col0 = bx * 256 + wn * 64 + fr;
#pragma unroll
  for (int n = 0; n < 4; ++n) {
    const int gc = col0 + n * 16;
    const float bv = bias[gc];
#pragma unroll
    for (int m = 0; m < 8; ++m) {
#pragma unroll
      for (int jj = 0; jj < 4; ++jj) {
        const size_t idx = (size_t)(row0 + m * 16 + jj) * NDIM + (size_t)gc;
        Cv[idx] = __builtin_bit_cast(u16, (__bf16)(acc[m][n][jj] + bv));
      }
    }
  }
}

// ---------------------------------------------------------------------------
// gemm8p: r9/r11 proven 8-phase bf16 GEMM (CVTP removed; used for gemmo).
// ---------------------------------------------------------------------------
#define PH_SYNC() do { SBAR0(); __builtin_amdgcn_s_barrier(); \
    asm volatile("s_waitcnt lgkmcnt(0)" ::: "memory"); SBAR0(); } while (0)
#define PH_END() do { SBAR0(); __builtin_amdgcn_s_barrier(); } while (0)
#define VM4() asm volatile("s_waitcnt vmcnt(4)" ::: "memory")
#define NKT 16

__global__ __launch_bounds__(512, 2) void gemm8p(const u16* __restrict__ Ab,
                                                 const u16* __restrict__ Bw,
                                                 const float* __restrict__ bias,
                                                 float* __restrict__ Cv,
                                                 int byPerXcd) {
  __shared__ __align__(16) unsigned char As[2][2][16384];
  __shared__ __align__(16) unsigned char Bs[2][2][16384];

  const int bid = (int)blockIdx.x;
  const int xcd = bid & 7;
  const int within = bid >> 3;
  const int by = xcd * byPerXcd + (within >> 2);
  const int bx = within & 3;

  const int t = (int)threadIdx.x;
  const int lane = t & 63;
  const int wid = t >> 6;
  const int wm = wid >> 2;
  const int wn = wid & 3;
  const int bh = wn >> 1;
  const int fr = lane & 15;
  const int hi = lane >> 4;

  size_t gOff[2]; int lOff[2];
#pragma unroll
  for (int i = 0; i < 2; ++i) {
    const int idx = i * 512 + t;
    const int r = idx >> 3, ch = idx & 7;
    gOff[i] = (size_t)r * KDIM + (size_t)((ch ^ (r & 7)) << 3);
    lOff[i] = (i * 512 + (t & ~63)) * 16;
  }
  const u16* Abase = Ab + (size_t)(by * 256) * KDIM;
  const u16* Bbase = Bw + (size_t)(bx * 256) * KDIM;

  auto SA = [&](int tile, int d, int h) {
    const u16* s = Abase + (size_t)(h * 128) * KDIM + tile * 64;
#pragma unroll
    for (int i = 0; i < 2; ++i) gload_lds16(s + gOff[i], &As[d][h][lOff[i]]);
  };
  auto SB = [&](int tile, int d, int h) {
    const u16* s = Bbase + (size_t)(h * 128) * KDIM + tile * 64;
#pragma unroll
    for (int i = 0; i < 2; ++i) gload_lds16(s + gOff[i], &Bs[d][h][lOff[i]]);
  };

  int aOff[8][2], bOff[4][2];
#pragma unroll
  for (int m = 0; m < 8; ++m)
#pragma unroll
    for (int ks = 0; ks < 2; ++ks)
      aOff[m][ks] = (m * 16 + fr) * 128 + (((ks * 4 + hi) ^ (fr & 7)) << 4);
#pragma unroll
  for (int n = 0; n < 4; ++n)
#pragma unroll
    for (int ks = 0; ks < 2; ++ks)
      bOff[n][ks] = ((wn & 1) * 64 + n * 16 + fr) * 128 + (((ks * 4 + hi) ^ (fr & 7)) << 4);

  f32x4 acc[8][4] = {};
  bf16x8 a[4], b[8];

  const unsigned char* Am0 = &As[0][wm][0];
  const unsigned char* Am1 = &As[1][wm][0];
  const unsigned char* Bm0 = &Bs[0][bh][0];
  const unsigned char* Bm1 = &Bs[1][bh][0];

  auto LDA4_0 = [&](int mlo, int ks) {
#pragma unroll
    for (int i = 0; i < 4; ++i)
      a[i] = *(const bf16x8*)((const void*)(Am0 + aOff[mlo + i][ks]));
  };
  auto LDA4_1 = [&](int mlo, int ks) {
#pragma unroll
    for (int i = 0; i < 4; ++i)
      a[i] = *(const bf16x8*)((const void*)(Am1 + aOff[mlo + i][ks]));
  };
  auto LDB8_0 = [&]() {
#pragma unroll
    for (int ks = 0; ks < 2; ++ks)
#pragma unroll
      for (int n = 0; n < 4; ++n)
        b[ks * 4 + n] = *(const bf16x8*)((const void*)(Bm0 + bOff[n][ks]));
  };
  auto LDB8_1 = [&]() {
#pragma unroll
    for (int ks = 0; ks < 2; ++ks)
#pragma unroll
      for (int n = 0; n < 4; ++n)
        b[ks * 4 + n] = *(const bf16x8*)((const void*)(Bm1 + bOff[n][ks]));
  };
  auto MM = [&](int mlo, int bo) {
    __builtin_amdgcn_s_setprio(1);
#pragma unroll
    for (int m = 0; m < 4; ++m)
#pragma unroll
      for (int n = 0; n < 4; ++n)
        acc[mlo + m][n] = __builtin_amdgcn_mfma_f32_16x16x32_bf16(
            a[m], b[bo + n], acc[mlo + m][n], 0, 0, 0);
    __builtin_amdgcn_s_setprio(0);
  };

  SB(0, 0, 0); SB(0, 0, 1); SA(0, 0, 0); SA(0, 0, 1);
  SB(1, 1, 0); SB(1, 1, 1);
  VM4(); SBAR0();
  __builtin_amdgcn_s_barrier();

  for (int j = 0; j < NKT / 2; ++j) {
    const int T1 = 2 * j + 1;
    const int T2 = (2 * j + 2 < NKT) ? 2 * j + 2 : NKT - 1;
    const int T3 = (2 * j + 3 < NKT) ? 2 * j + 3 : NKT - 1;

    LDB8_0(); LDA4_0(0, 0);
    SA(T1, 1, 0);
    PH_SYNC(); MM(0, 0); PH_END();

    LDA4_0(4, 0);
    SA(T1, 1, 1);
    PH_SYNC(); MM(4, 0); PH_END();

    LDA4_0(0, 1);
    SB(T2, 0, 0);
    PH_SYNC(); MM(0, 4); PH_END();

    LDA4_0(4, 1);
    SB(T2, 0, 1);
    PH_SYNC(); MM(4, 4);
    VM4(); PH_END();

    LDB8_1(); LDA4_1(0, 0);
    SA(T2, 0, 0);
    PH_SYNC(); MM(0, 0); PH_END();

    LDA4_1(4, 0);
    SA(T2, 0, 1);
    PH_SYNC(); MM(4, 0); PH_END();

    LDA4_1(0, 1);
    SB(T3, 1, 0);
    PH_SYNC(); MM(0, 4); PH_END();

    LDA4_1(4, 1);
    SB(T3, 1, 1);
    PH_SYNC(); MM(4, 4);
    VM4(); PH_END();
  }
  asm volatile("s_waitcnt vmcnt(0)" ::: "memory");

  const int row0 = by * 256 + wm * 128 + hi * 4;
  const int col0 = bx * 256 + wn * 64 + fr;
#pragma unroll
  for (int n = 0; n < 4; ++n) {
    const int gc = col0 + n * 16;
    const float bv = bias[gc];
#pragma unroll
    for (int m = 0; m < 8; ++m) {
#pragma unroll
      for (int jj = 0; jj < 4; ++jj) {
        const size_t idx = (size_t)(row0 + m * 16 + jj) * NDIM + (size_t)gc;
        Cv[idx] = acc[m][n][jj] + bv;
      }
    }
  }
}

// One wave per (b,l,h) attention unit: 8x8 scores over DK=64, softmax over e,
// PV, write x in-place over q (disjoint columns per head -> race-free).
__global__ __launch_bounds__(256) void attn_kernel(u16* __restrict__ qx,
                                                   const u16* __restrict__ kb,
                                                   const u16* __restrict__ vb) {
  __shared__ __align__(16) u16 qs[4][8][64];
  __shared__ __align__(16) u16 ks[4][8][64];
  __shared__ __align__(16) u16 vs[4][8][64];
  const int t = threadIdx.x;
  const int lane = t & 63;
  const int w = t >> 6;
  const int unit = blockIdx.x * 4 + w;
  const int bl = unit >> 4;
  const int h = unit & 15;
  const int row = lane >> 3;
  const int c8 = (lane & 7) * 8;
  const size_t goff = (size_t)bl * 8 * 1024 + (size_t)h * 64 + (size_t)row * 1024 + c8;

  *(int4*)((void*)&qs[w][row][c8]) = *(const int4*)((const void*)&qx[goff]);
  *(int4*)((void*)&ks[w][row][c8]) = *(const int4*)((const void*)&kb[goff]);
  *(int4*)((void*)&vs[w][row][c8]) = *(const int4*)((const void*)&vb[goff]);
  __syncthreads();

  const int a = row;
  const int e = lane & 7;
  float s = 0.f;
#pragma unroll
  for (int d8 = 0; d8 < 64; d8 += 8) {
    const bf16x8 qv = *(const bf16x8*)((const void*)&qs[w][a][d8]);
    const bf16x8 kv = *(const bf16x8*)((const void*)&ks[w][e][d8]);
#pragma unroll
    for (int j = 0; j < 8; ++j) s += (float)qv[j] * (float)kv[j];
  }
  s *= 0.125f;

  float mx = s;
#pragma unroll
  for (int o = 1; o < 8; o <<= 1) mx = fmaxf(mx, __shfl_xor(mx, o));
  float p = __expf(s - mx);
  float sum = p;
#pragma unroll
  for (int o = 1; o < 8; o <<= 1) sum += __shfl_xor(sum, o);
  p /= sum;

  float xo[8] = {};
#pragma unroll
  for (int e2 = 0; e2 < 8; ++e2) {
    const float pe = __shfl(p, (lane & 56) + e2);
    const bf16x8 vv = *(const bf16x8*)((const void*)&vs[w][e2][c8]);
#pragma unroll
    for (int j = 0; j < 8; ++j) xo[j] += pe * (float)vv[j];
  }
  bf16x8 hx;
#pragma unroll
  for (int j = 0; j < 8; ++j) hx[j] = (__bf16)xo[j];
  *(int4*)((void*)&qx[goff]) = __builtin_bit_cast(int4, hx);
}

extern "C" void kernel_launch(void* const* d_in, const int* in_sizes, int n_in,
                              void* d_out, int out_size, void* d_ws, size_t ws_size,
                              hipStream_t stream) {
  const float* query = (const float*)d_in[0];
  const float* key   = (const float*)d_in[1];
  const float* value = (const float*)d_in[2];
  const float* Wq = (const float*)d_in[3];
  const float* bq = (const float*)d_in[4];
  const float* Wk = (const float*)d_in[5];
  const float* bk = (const float*)d_in[6];
  const float* Wv = (const float*)d_in[7];
  const float* bv = (const float*)d_in[8];
  const float* Wo = (const float*)d_in[9];
  const float* bo = (const float*)d_in[10];
  (void)in_sizes; (void)n_in; (void)out_size; (void)ws_size;

  const size_t mn = (size_t)MROWS * (size_t)NDIM;

  // d_out holds kb+vb (bf16) until attn consumes them; gemmo then overwrites
  // d_out with fp32. ws: qb (67MB) + bf16 weights (8MB) = 75MB.
  u16* kb = (u16*)d_out;
  u16* vb = kb + mn;
  u16* qb = (u16*)d_ws;
  u16* Wqb = qb + mn;
  u16* Wkb = Wqb + 1048576;
  u16* Wvb = Wkb + 1048576;
  u16* Wob = Wvb + 1048576;

  CvtArgs ca;
  ca.s[0] = Wq; ca.s[1] = Wk; ca.s[2] = Wv; ca.s[3] = Wo;
  ca.d[0] = Wqb; ca.d[1] = Wkb; ca.d[2] = Wvb; ca.d[3] = Wob;
  cvt4_kernel<<<2048, 256, 0, stream>>>(ca);

  // Projections read fp32 inputs DIRECTLY (no input staging pass).
  gemm8f<<<512, 512, 0, stream>>>(key,   Wkb, bk, kb, 16);
  gemm8f<<<512, 512, 0, stream>>>(value, Wvb, bv, vb, 16);
  gemm8f<<<512, 512, 0, stream>>>(query, Wqb, bq, qb, 16);

  attn_kernel<<<16384, 256, 0, stream>>>(qb, kb, vb);

  gemm8p<<<512, 512, 0, stream>>>(qb, Wob, bo, (float*)d_out, 16);
}

// Round 13
// 511.389 us; speedup vs baseline: 1.0020x; 1.0020x over previous
//
#include <hip/hip_runtime.h>
#include <hip/hip_bf16.h>
#include <stdint.h>

typedef unsigned short u16;
typedef __bf16 bf16x8 __attribute__((ext_vector_type(8)));
typedef float f32x4 __attribute__((ext_vector_type(4)));

// B=4, L=1024, A=8, D=1024, H=16, DK=64
#define MROWS 32768   // B*L*A
#define NDIM  1024
#define KDIM  1024

__device__ __forceinline__ void gload_lds16(const void* g, void* l) {
  __builtin_amdgcn_global_load_lds(
      (__attribute__((address_space(1))) const void*)g,
      (__attribute__((address_space(3))) void*)l,
      16, 0, 0);
}

struct CvtArgs { const float* s[4]; u16* d[4]; };

// weights fp32 -> bf16 (4 x 1M elems; 512 blocks per matrix)
__global__ __launch_bounds__(256) void cvt4_kernel(CvtArgs ca) {
  const int which = blockIdx.x >> 9;
  const float* s = ca.s[which];
  u16* d = ca.d[which];
  const int i = ((((int)blockIdx.x & 511) * 256) + (int)threadIdx.x) * 8;
  const float4 f0 = *(const float4*)(s + i);
  const float4 f1 = *(const float4*)(s + i + 4);
  bf16x8 h;
  h[0] = (__bf16)f0.x; h[1] = (__bf16)f0.y; h[2] = (__bf16)f0.z; h[3] = (__bf16)f0.w;
  h[4] = (__bf16)f1.x; h[5] = (__bf16)f1.y; h[6] = (__bf16)f1.z; h[7] = (__bf16)f1.w;
  *(bf16x8*)((void*)(d + i)) = h;
}

#define SBAR0() __builtin_amdgcn_sched_barrier(0)
#define VM6() asm volatile("s_waitcnt vmcnt(6)" ::: "memory")

// ---------------------------------------------------------------------------
// gemm8f: C[m,n] = sum_k A_f32[m,k]*B_bf16[n,k] + bias[n], C bf16.
// r12 structure (passed, post-timing-stable) with the B-swizzle FIXED:
// 64B rows need chunk ^ ((row>>1)&3) (r4's proven layout; quarter-wave
// bank spread 2-way=free), NOT chunk ^ (row&3) (measured 4-way, 1.05e7
// conflicts, the r12 regression). A fp32 [256][32f] 128B rows with
// chunk ^ (row&7) is quarter-wave 2-way (verified free by the same model
// that matches gemm8p's measured 0).
// One phase per K-tile (BK=32, 32 tiles), dbuf LDS 96KB:
//   { latch all frags (16 f32x4 A + cvt, 4 B b128); lgkmcnt(0); barrier;
//     stage tile t+2 into this buf (6 gload_lds); setprio(1); 32 MFMA;
//     setprio(0); vmcnt(6); barrier }
// ---------------------------------------------------------------------------
__global__ __launch_bounds__(512, 2) void gemm8f(const float* __restrict__ Af,
                                                 const u16* __restrict__ Bw,
                                                 const float* __restrict__ bias,
                                                 u16* __restrict__ Cv,
                                                 int byPerXcd) {
  __shared__ __align__(16) unsigned char As[2][32768];
  __shared__ __align__(16) unsigned char Bs[2][16384];

  const int bid = (int)blockIdx.x;
  const int xcd = bid & 7;
  const int within = bid >> 3;
  const int by = xcd * byPerXcd + (within >> 2);
  const int bx = within & 3;

  const int t = (int)threadIdx.x;
  const int lane = t & 63;
  const int wid = t >> 6;
  const int wm = wid >> 2;        // 0..1 (M half)
  const int wn = wid & 3;         // 0..3 (N quarter)
  const int fr = lane & 15;
  const int hi = lane >> 4;

  // staging descriptors (pre-swizzled source, linear LDS dest)
  size_t aG[4]; int aL[4];
#pragma unroll
  for (int i = 0; i < 4; ++i) {
    const int idx = i * 512 + t;
    const int r = idx >> 3, ch = idx & 7;
    aG[i] = (size_t)r * KDIM + (size_t)((ch ^ (r & 7)) << 2);   // float units
    aL[i] = (i * 512 + (t & ~63)) * 16;
  }
  size_t bG[2]; int bL[2];
#pragma unroll
  for (int i = 0; i < 2; ++i) {
    const int idx = i * 512 + t;
    const int r = idx >> 2, ch = idx & 3;
    bG[i] = (size_t)r * KDIM + (size_t)((ch ^ ((r >> 1) & 3)) << 3);  // u16 units
    bL[i] = (i * 512 + (t & ~63)) * 16;
  }
  const float* Abase = Af + (size_t)(by * 256) * KDIM;
  const u16* Bbase = Bw + (size_t)(bx * 256) * KDIM;

  auto SA = [&](int tile, int d) {
    const float* s = Abase + tile * 32;
#pragma unroll
    for (int i = 0; i < 4; ++i) gload_lds16(s + aG[i], &As[d][aL[i]]);
  };
  auto SB = [&](int tile, int d) {
    const u16* s = Bbase + tile * 32;
#pragma unroll
    for (int i = 0; i < 2; ++i) gload_lds16(s + bG[i], &Bs[d][bL[i]]);
  };

  // fragment read offsets
  int aOffF[8][2];
#pragma unroll
  for (int m = 0; m < 8; ++m)
#pragma unroll
    for (int c = 0; c < 2; ++c)
      aOffF[m][c] = (wm * 128 + m * 16 + fr) * 128 + (((hi * 2 + c) ^ (fr & 7)) << 4);
  int bOffF[4];
#pragma unroll
  for (int n = 0; n < 4; ++n)
    bOffF[n] = (wn * 64 + n * 16 + fr) * 64 + ((hi ^ ((fr >> 1) & 3)) << 4);

  f32x4 acc[8][4] = {};

  // PROLOGUE: stage tiles 0,1; wait tile0 (6 of 12 -> counted).
  SA(0, 0); SB(0, 0); SA(1, 1); SB(1, 1);
  VM6(); SBAR0();
  __builtin_amdgcn_s_barrier();

  for (int kt = 0; kt < 32; ++kt) {
    const int d = kt & 1;

    // latch all fragments (reads of buf d) + cvt A to bf16
    bf16x8 a8[8], b4[4];
#pragma unroll
    for (int m = 0; m < 8; ++m) {
      const f32x4 x0 = *(const f32x4*)((const void*)(As[d] + aOffF[m][0]));
      const f32x4 x1 = *(const f32x4*)((const void*)(As[d] + aOffF[m][1]));
      bf16x8 h;
      h[0] = (__bf16)x0[0]; h[1] = (__bf16)x0[1]; h[2] = (__bf16)x0[2]; h[3] = (__bf16)x0[3];
      h[4] = (__bf16)x1[0]; h[5] = (__bf16)x1[1]; h[6] = (__bf16)x1[2]; h[7] = (__bf16)x1[3];
      a8[m] = h;
    }
#pragma unroll
    for (int n = 0; n < 4; ++n)
      b4[n] = *(const bf16x8*)((const void*)(Bs[d] + bOffF[n]));

    asm volatile("s_waitcnt lgkmcnt(0)" ::: "memory");   // own reads done
    SBAR0();
    __builtin_amdgcn_s_barrier();                        // ALL waves' reads done
    SBAR0();

    // stage tile kt+2 into buf d (reads complete chip-wide; clamped tail
    // restage is a harmless write to a dead/finished buffer).
    const int tn = (kt + 2 < 32) ? kt + 2 : 31;
    SA(tn, d); SB(tn, d);

    __builtin_amdgcn_s_setprio(1);
#pragma unroll
    for (int m = 0; m < 8; ++m)
#pragma unroll
      for (int n = 0; n < 4; ++n)
        acc[m][n] = __builtin_amdgcn_mfma_f32_16x16x32_bf16(a8[m], b4[n], acc[m][n], 0, 0, 0);
    __builtin_amdgcn_s_setprio(0);

    VM6();                                               // tile kt+1 landed
    SBAR0();
    __builtin_amdgcn_s_barrier();
  }

  // epilogue: D col = fr (N), row = hi*4 + jj (M); C bf16 + bias
  const int row0 = by * 256 + wm * 128 + hi * 4;
  const int col0 = bx * 256 + wn * 64 + fr;
#pragma unroll
  for (int n = 0; n < 4; ++n) {
    const int gc = col0 + n * 16;
    const float bv = bias[gc];
#pragma unroll
    for (int m = 0; m < 8; ++m) {
#pragma unroll
      for (int jj = 0; jj < 4; ++jj) {
        const size_t idx = (size_t)(row0 + m * 16 + jj) * NDIM + (size_t)gc;
        Cv[idx] = __builtin_bit_cast(u16, (__bf16)(acc[m][n][jj] + bv));
      }
    }
  }
}

// ---------------------------------------------------------------------------
// gemm8p: r9/r11 proven 8-phase bf16 GEMM (used for gemmo).
// ---------------------------------------------------------------------------
#define PH_SYNC() do { SBAR0(); __builtin_amdgcn_s_barrier(); \
    asm volatile("s_waitcnt lgkmcnt(0)" ::: "memory"); SBAR0(); } while (0)
#define PH_END() do { SBAR0(); __builtin_amdgcn_s_barrier(); } while (0)
#define VM4() asm volatile("s_waitcnt vmcnt(4)" ::: "memory")
#define NKT 16

__global__ __launch_bounds__(512, 2) void gemm8p(const u16* __restrict__ Ab,
                                                 const u16* __restrict__ Bw,
                                                 const float* __restrict__ bias,
                                                 float* __restrict__ Cv,
                                                 int byPerXcd) {
  __shared__ __align__(16) unsigned char As[2][2][16384];
  __shared__ __align__(16) unsigned char Bs[2][2][16384];

  const int bid = (int)blockIdx.x;
  const int xcd = bid & 7;
  const int within = bid >> 3;
  const int by = xcd * byPerXcd + (within >> 2);
  const int bx = within & 3;

  const int t = (int)threadIdx.x;
  const int lane = t & 63;
  const int wid = t >> 6;
  const int wm = wid >> 2;
  const int wn = wid & 3;
  const int bh = wn >> 1;
  const int fr = lane & 15;
  const int hi = lane >> 4;

  size_t gOff[2]; int lOff[2];
#pragma unroll
  for (int i = 0; i < 2; ++i) {
    const int idx = i * 512 + t;
    const int r = idx >> 3, ch = idx & 7;
    gOff[i] = (size_t)r * KDIM + (size_t)((ch ^ (r & 7)) << 3);
    lOff[i] = (i * 512 + (t & ~63)) * 16;
  }
  const u16* Abase = Ab + (size_t)(by * 256) * KDIM;
  const u16* Bbase = Bw + (size_t)(bx * 256) * KDIM;

  auto SA = [&](int tile, int d, int h) {
    const u16* s = Abase + (size_t)(h * 128) * KDIM + tile * 64;
#pragma unroll
    for (int i = 0; i < 2; ++i) gload_lds16(s + gOff[i], &As[d][h][lOff[i]]);
  };
  auto SB = [&](int tile, int d, int h) {
    const u16* s = Bbase + (size_t)(h * 128) * KDIM + tile * 64;
#pragma unroll
    for (int i = 0; i < 2; ++i) gload_lds16(s + gOff[i], &Bs[d][h][lOff[i]]);
  };

  int aOff[8][2], bOff[4][2];
#pragma unroll
  for (int m = 0; m < 8; ++m)
#pragma unroll
    for (int ks = 0; ks < 2; ++ks)
      aOff[m][ks] = (m * 16 + fr) * 128 + (((ks * 4 + hi) ^ (fr & 7)) << 4);
#pragma unroll
  for (int n = 0; n < 4; ++n)
#pragma unroll
    for (int ks = 0; ks < 2; ++ks)
      bOff[n][ks] = ((wn & 1) * 64 + n * 16 + fr) * 128 + (((ks * 4 + hi) ^ (fr & 7)) << 4);

  f32x4 acc[8][4] = {};
  bf16x8 a[4], b[8];

  const unsigned char* Am0 = &As[0][wm][0];
  const unsigned char* Am1 = &As[1][wm][0];
  const unsigned char* Bm0 = &Bs[0][bh][0];
  const unsigned char* Bm1 = &Bs[1][bh][0];

  auto LDA4_0 = [&](int mlo, int ks) {
#pragma unroll
    for (int i = 0; i < 4; ++i)
      a[i] = *(const bf16x8*)((const void*)(Am0 + aOff[mlo + i][ks]));
  };
  auto LDA4_1 = [&](int mlo, int ks) {
#pragma unroll
    for (int i = 0; i < 4; ++i)
      a[i] = *(const bf16x8*)((const void*)(Am1 + aOff[mlo + i][ks]));
  };
  auto LDB8_0 = [&]() {
#pragma unroll
    for (int ks = 0; ks < 2; ++ks)
#pragma unroll
      for (int n = 0; n < 4; ++n)
        b[ks * 4 + n] = *(const bf16x8*)((const void*)(Bm0 + bOff[n][ks]));
  };
  auto LDB8_1 = [&]() {
#pragma unroll
    for (int ks = 0; ks < 2; ++ks)
#pragma unroll
      for (int n = 0; n < 4; ++n)
        b[ks * 4 + n] = *(const bf16x8*)((const void*)(Bm1 + bOff[n][ks]));
  };
  auto MM = [&](int mlo, int bo) {
    __builtin_amdgcn_s_setprio(1);
#pragma unroll
    for (int m = 0; m < 4; ++m)
#pragma unroll
      for (int n = 0; n < 4; ++n)
        acc[mlo + m][n] = __builtin_amdgcn_mfma_f32_16x16x32_bf16(
            a[m], b[bo + n], acc[mlo + m][n], 0, 0, 0);
    __builtin_amdgcn_s_setprio(0);
  };

  SB(0, 0, 0); SB(0, 0, 1); SA(0, 0, 0); SA(0, 0, 1);
  SB(1, 1, 0); SB(1, 1, 1);
  VM4(); SBAR0();
  __builtin_amdgcn_s_barrier();

  for (int j = 0; j < NKT / 2; ++j) {
    const int T1 = 2 * j + 1;
    const int T2 = (2 * j + 2 < NKT) ? 2 * j + 2 : NKT - 1;
    const int T3 = (2 * j + 3 < NKT) ? 2 * j + 3 : NKT - 1;

    LDB8_0(); LDA4_0(0, 0);
    SA(T1, 1, 0);
    PH_SYNC(); MM(0, 0); PH_END();

    LDA4_0(4, 0);
    SA(T1, 1, 1);
    PH_SYNC(); MM(4, 0); PH_END();

    LDA4_0(0, 1);
    SB(T2, 0, 0);
    PH_SYNC(); MM(0, 4); PH_END();

    LDA4_0(4, 1);
    SB(T2, 0, 1);
    PH_SYNC(); MM(4, 4);
    VM4(); PH_END();

    LDB8_1(); LDA4_1(0, 0);
    SA(T2, 0, 0);
    PH_SYNC(); MM(0, 0); PH_END();

    LDA4_1(4, 0);
    SA(T2, 0, 1);
    PH_SYNC(); MM(4, 0); PH_END();

    LDA4_1(0, 1);
    SB(T3, 1, 0);
    PH_SYNC(); MM(0, 4); PH_END();

    LDA4_1(4, 1);
    SB(T3, 1, 1);
    PH_SYNC(); MM(4, 4);
    VM4(); PH_END();
  }
  asm volatile("s_waitcnt vmcnt(0)" ::: "memory");

  const int row0 = by * 256 + wm * 128 + hi * 4;
  const int col0 = bx * 256 + wn * 64 + fr;
#pragma unroll
  for (int n = 0; n < 4; ++n) {
    const int gc = col0 + n * 16;
    const float bv = bias[gc];
#pragma unroll
    for (int m = 0; m < 8; ++m) {
#pragma unroll
      for (int jj = 0; jj < 4; ++jj) {
        const size_t idx = (size_t)(row0 + m * 16 + jj) * NDIM + (size_t)gc;
        Cv[idx] = acc[m][n][jj] + bv;
      }
    }
  }
}

// One wave per (b,l,h) attention unit: 8x8 scores over DK=64, softmax over e,
// PV, write x in-place over q (disjoint columns per head -> race-free).
__global__ __launch_bounds__(256) void attn_kernel(u16* __restrict__ qx,
                                                   const u16* __restrict__ kb,
                                                   const u16* __restrict__ vb) {
  __shared__ __align__(16) u16 qs[4][8][64];
  __shared__ __align__(16) u16 ks[4][8][64];
  __shared__ __align__(16) u16 vs[4][8][64];
  const int t = threadIdx.x;
  const int lane = t & 63;
  const int w = t >> 6;
  const int unit = blockIdx.x * 4 + w;
  const int bl = unit >> 4;
  const int h = unit & 15;
  const int row = lane >> 3;
  const int c8 = (lane & 7) * 8;
  const size_t goff = (size_t)bl * 8 * 1024 + (size_t)h * 64 + (size_t)row * 1024 + c8;

  *(int4*)((void*)&qs[w][row][c8]) = *(const int4*)((const void*)&qx[goff]);
  *(int4*)((void*)&ks[w][row][c8]) = *(const int4*)((const void*)&kb[goff]);
  *(int4*)((void*)&vs[w][row][c8]) = *(const int4*)((const void*)&vb[goff]);
  __syncthreads();

  const int a = row;
  const int e = lane & 7;
  float s = 0.f;
#pragma unroll
  for (int d8 = 0; d8 < 64; d8 += 8) {
    const bf16x8 qv = *(const bf16x8*)((const void*)&qs[w][a][d8]);
    const bf16x8 kv = *(const bf16x8*)((const void*)&ks[w][e][d8]);
#pragma unroll
    for (int j = 0; j < 8; ++j) s += (float)qv[j] * (float)kv[j];
  }
  s *= 0.125f;

  float mx = s;
#pragma unroll
  for (int o = 1; o < 8; o <<= 1) mx = fmaxf(mx, __shfl_xor(mx, o));
  float p = __expf(s - mx);
  float sum = p;
#pragma unroll
  for (int o = 1; o < 8; o <<= 1) sum += __shfl_xor(sum, o);
  p /= sum;

  float xo[8] = {};
#pragma unroll
  for (int e2 = 0; e2 < 8; ++e2) {
    const float pe = __shfl(p, (lane & 56) + e2);
    const bf16x8 vv = *(const bf16x8*)((const void*)&vs[w][e2][c8]);
#pragma unroll
    for (int j = 0; j < 8; ++j) xo[j] += pe * (float)vv[j];
  }
  bf16x8 hx;
#pragma unroll
  for (int j = 0; j < 8; ++j) hx[j] = (__bf16)xo[j];
  *(int4*)((void*)&qx[goff]) = __builtin_bit_cast(int4, hx);
}

extern "C" void kernel_launch(void* const* d_in, const int* in_sizes, int n_in,
                              void* d_out, int out_size, void* d_ws, size_t ws_size,
                              hipStream_t stream) {
  const float* query = (const float*)d_in[0];
  const float* key   = (const float*)d_in[1];
  const float* value = (const float*)d_in[2];
  const float* Wq = (const float*)d_in[3];
  const float* bq = (const float*)d_in[4];
  const float* Wk = (const float*)d_in[5];
  const float* bk = (const float*)d_in[6];
  const float* Wv = (const float*)d_in[7];
  const float* bv = (const float*)d_in[8];
  const float* Wo = (const float*)d_in[9];
  const float* bo = (const float*)d_in[10];
  (void)in_sizes; (void)n_in; (void)out_size; (void)ws_size;

  const size_t mn = (size_t)MROWS * (size_t)NDIM;

  // d_out holds kb+vb (bf16) until attn consumes them; gemmo then overwrites
  // d_out with fp32. ws: qb (67MB) + bf16 weights (8MB) = 75MB.
  u16* kb = (u16*)d_out;
  u16* vb = kb + mn;
  u16* qb = (u16*)d_ws;
  u16* Wqb = qb + mn;
  u16* Wkb = Wqb + 1048576;
  u16* Wvb = Wkb + 1048576;
  u16* Wob = Wvb + 1048576;

  CvtArgs ca;
  ca.s[0] = Wq; ca.s[1] = Wk; ca.s[2] = Wv; ca.s[3] = Wo;
  ca.d[0] = Wqb; ca.d[1] = Wkb; ca.d[2] = Wvb; ca.d[3] = Wob;
  cvt4_kernel<<<2048, 256, 0, stream>>>(ca);

  // Projections read fp32 inputs DIRECTLY (no input staging pass).
  gemm8f<<<512, 512, 0, stream>>>(key,   Wkb, bk, kb, 16);
  gemm8f<<<512, 512, 0, stream>>>(value, Wvb, bv, vb, 16);
  gemm8f<<<512, 512, 0, stream>>>(query, Wqb, bq, qb, 16);

  attn_kernel<<<16384, 256, 0, stream>>>(qb, kb, vb);

  gemm8p<<<512, 512, 0, stream>>>(qb, Wob, bo, (float*)d_out, 16);
}

// Round 14
// 455.185 us; speedup vs baseline: 1.1258x; 1.1235x over previous
//
#include <hip/hip_runtime.h>
#include <hip/hip_bf16.h>
#include <stdint.h>

typedef unsigned short u16;
typedef __bf16 bf16x8 __attribute__((ext_vector_type(8)));
typedef float f32x4 __attribute__((ext_vector_type(4)));

// B=4, L=1024, A=8, D=1024, H=16, DK=64
#define MROWS 32768   // B*L*A
#define NDIM  1024
#define KDIM  1024
#define NKT   16      // K-tiles of BK=64
#define MHALF 16777216

__device__ __forceinline__ void gload_lds16(const void* g, void* l) {
  __builtin_amdgcn_global_load_lds(
      (__attribute__((address_space(1))) const void*)g,
      (__attribute__((address_space(3))) void*)l,
      16, 0, 0);
}

struct CvtArgs { const float* s[4]; u16* d[4]; };

// Fused: blocks [0,8192) convert key_h1 (16.78M elems); blocks [8192,10240)
// convert the four 1M-elem weight matrices.
__global__ __launch_bounds__(256) void cvt_kw_kernel(const float* __restrict__ key,
                                                     u16* __restrict__ dkey,
                                                     CvtArgs ca) {
  const int bid = (int)blockIdx.x;
  const float* s; u16* d; int i;
  if (bid < 8192) {
    s = key; d = dkey;
    i = (bid * 256 + (int)threadIdx.x) * 8;
  } else {
    const int b2 = bid - 8192;
    const int which = b2 >> 9;
    s = ca.s[which]; d = ca.d[which];
    i = ((b2 & 511) * 256 + (int)threadIdx.x) * 8;
  }
  const float4 f0 = *(const float4*)(s + i);
  const float4 f1 = *(const float4*)(s + i + 4);
  bf16x8 h;
  h[0] = (__bf16)f0.x; h[1] = (__bf16)f0.y; h[2] = (__bf16)f0.z; h[3] = (__bf16)f0.w;
  h[4] = (__bf16)f1.x; h[5] = (__bf16)f1.y; h[6] = (__bf16)f1.z; h[7] = (__bf16)f1.w;
  *(bf16x8*)((void*)(d + i)) = h;
}

// ---------------------------------------------------------------------------
// 8-phase 256x256 NT GEMM (r9/r10/r11 structure, verified stable across
// timed replays) + dribbled cvt: per 2-K-tile iteration each thread loads
// CVTP*2 float4 of the NEXT input at iter-top (drained by the existing VM4
// waits; ledger verified) and stores CVTP bf16x8 after ph8's VM4. Core
// schedule: B-read-once (ph1/ph5 latch all 8 B-frags), stage windows
// ph1-2->T1.A(d1), ph3-4->T2.B(d0), ph5-6->T2.A(d0), ph7-8->T3.B(d1),
// vmcnt(4) at ph4/ph8 only, sched_barrier(0) fencing, chunk^(row&7) LDS
// swizzle on both sides (0 conflicts measured).
// ---------------------------------------------------------------------------
#define SBAR0() __builtin_amdgcn_sched_barrier(0)
#define PH_SYNC() do { SBAR0(); __builtin_amdgcn_s_barrier(); \
    asm volatile("s_waitcnt lgkmcnt(0)" ::: "memory"); SBAR0(); } while (0)
#define PH_END() do { SBAR0(); __builtin_amdgcn_s_barrier(); } while (0)
#define VM4() asm volatile("s_waitcnt vmcnt(4)" ::: "memory")

template <bool OUT_F32, int CVTP>
__global__ __launch_bounds__(512, 2) void gemm8p(const u16* __restrict__ Ab,
                                                 const u16* __restrict__ Bw,
                                                 const float* __restrict__ bias,
                                                 void* __restrict__ Cv,
                                                 int byPerXcd,
                                                 const float* __restrict__ cvt_src,
                                                 u16* __restrict__ cvt_dst) {
  __shared__ __align__(16) unsigned char As[2][2][16384];
  __shared__ __align__(16) unsigned char Bs[2][2][16384];

  const int bid = (int)blockIdx.x;
  const int xcd = bid & 7;
  const int within = bid >> 3;
  const int by = xcd * byPerXcd + (within >> 2);
  const int bx = within & 3;

  const int t = (int)threadIdx.x;
  const int lane = t & 63;
  const int wid = t >> 6;
  const int wm = wid >> 2;        // A-half (M)
  const int wn = wid & 3;
  const int bh = wn >> 1;         // B-half (N)
  const int fr = lane & 15;
  const int hi = lane >> 4;

  size_t gOff[2]; int lOff[2];
#pragma unroll
  for (int i = 0; i < 2; ++i) {
    const int idx = i * 512 + t;
    const int r = idx >> 3, ch = idx & 7;
    gOff[i] = (size_t)r * KDIM + (size_t)((ch ^ (r & 7)) << 3);
    lOff[i] = (i * 512 + (t & ~63)) * 16;
  }
  const u16* Abase = Ab + (size_t)(by * 256) * KDIM;
  const u16* Bbase = Bw + (size_t)(bx * 256) * KDIM;

  auto SA = [&](int tile, int d, int h) {
    const u16* s = Abase + (size_t)(h * 128) * KDIM + tile * 64;
#pragma unroll
    for (int i = 0; i < 2; ++i) gload_lds16(s + gOff[i], &As[d][h][lOff[i]]);
  };
  auto SB = [&](int tile, int d, int h) {
    const u16* s = Bbase + (size_t)(h * 128) * KDIM + tile * 64;
#pragma unroll
    for (int i = 0; i < 2; ++i) gload_lds16(s + gOff[i], &Bs[d][h][lOff[i]]);
  };

  int aOff[8][2], bOff[4][2];
#pragma unroll
  for (int m = 0; m < 8; ++m)
#pragma unroll
    for (int ks = 0; ks < 2; ++ks)
      aOff[m][ks] = (m * 16 + fr) * 128 + (((ks * 4 + hi) ^ (fr & 7)) << 4);
#pragma unroll
  for (int n = 0; n < 4; ++n)
#pragma unroll
    for (int ks = 0; ks < 2; ++ks)
      bOff[n][ks] = ((wn & 1) * 64 + n * 16 + fr) * 128 + (((ks * 4 + hi) ^ (fr & 7)) << 4);

  f32x4 acc[8][4] = {};
  bf16x8 a[4], b[8];

  const unsigned char* Am0 = &As[0][wm][0];
  const unsigned char* Am1 = &As[1][wm][0];
  const unsigned char* Bm0 = &Bs[0][bh][0];
  const unsigned char* Bm1 = &Bs[1][bh][0];

  auto LDA4_0 = [&](int mlo, int ks) {
#pragma unroll
    for (int i = 0; i < 4; ++i)
      a[i] = *(const bf16x8*)((const void*)(Am0 + aOff[mlo + i][ks]));
  };
  auto LDA4_1 = [&](int mlo, int ks) {
#pragma unroll
    for (int i = 0; i < 4; ++i)
      a[i] = *(const bf16x8*)((const void*)(Am1 + aOff[mlo + i][ks]));
  };
  auto LDB8_0 = [&]() {
#pragma unroll
    for (int ks = 0; ks < 2; ++ks)
#pragma unroll
      for (int n = 0; n < 4; ++n)
        b[ks * 4 + n] = *(const bf16x8*)((const void*)(Bm0 + bOff[n][ks]));
  };
  auto LDB8_1 = [&]() {
#pragma unroll
    for (int ks = 0; ks < 2; ++ks)
#pragma unroll
      for (int n = 0; n < 4; ++n)
        b[ks * 4 + n] = *(const bf16x8*)((const void*)(Bm1 + bOff[n][ks]));
  };
  auto MM = [&](int mlo, int bo) {
    __builtin_amdgcn_s_setprio(1);
#pragma unroll
    for (int m = 0; m < 4; ++m)
#pragma unroll
      for (int n = 0; n < 4; ++n)
        acc[mlo + m][n] = __builtin_amdgcn_mfma_f32_16x16x32_bf16(
            a[m], b[bo + n], acc[mlo + m][n], 0, 0, 0);
    __builtin_amdgcn_s_setprio(0);
  };

  const int ngrid = (int)gridDim.x;

  // PROLOGUE: T0 all 4 halves + T1.B both halves; land T0 (vmcnt(4)).
  SB(0, 0, 0); SB(0, 0, 1); SA(0, 0, 0); SA(0, 0, 1);
  SB(1, 1, 0); SB(1, 1, 1);
  VM4(); SBAR0();
  __builtin_amdgcn_s_barrier();

  for (int j = 0; j < NKT / 2; ++j) {
    const int T1 = 2 * j + 1;
    const int T2 = (2 * j + 2 < NKT) ? 2 * j + 2 : NKT - 1;
    const int T3 = (2 * j + 3 < NKT) ? 2 * j + 3 : NKT - 1;

    // dribbled cvt: issue next-input loads FIRST (oldest in vmcnt FIFO ->
    // drained by VM4@ph4 with no added ledger slack).
    float4 cf[CVTP ? CVTP : 1][2];
    if constexpr (CVTP > 0) {
#pragma unroll
      for (int p = 0; p < CVTP; ++p) {
        const size_t b8i = ((size_t)(j * CVTP + p) * ngrid + bid) * 512 + t;
        cf[p][0] = ((const float4*)cvt_src)[b8i * 2];
        cf[p][1] = ((const float4*)cvt_src)[b8i * 2 + 1];
      }
    }

    // ---- tile 2j (d0) ----
    LDB8_0(); LDA4_0(0, 0);           // ph1: latch B all + A m0-3 ks0
    SA(T1, 1, 0);
    PH_SYNC(); MM(0, 0); PH_END();

    LDA4_0(4, 0);                     // ph2
    SA(T1, 1, 1);
    PH_SYNC(); MM(4, 0); PH_END();

    LDA4_0(0, 1);                     // ph3
    SB(T2, 0, 0);
    PH_SYNC(); MM(0, 4); PH_END();

    LDA4_0(4, 1);                     // ph4
    SB(T2, 0, 1);
    PH_SYNC(); MM(4, 4);
    VM4(); PH_END();                  // T1 fully landed

    // ---- tile 2j+1 (d1) ----
    LDB8_1(); LDA4_1(0, 0);           // ph5
    SA(T2, 0, 0);
    PH_SYNC(); MM(0, 0); PH_END();

    LDA4_1(4, 0);                     // ph6
    SA(T2, 0, 1);
    PH_SYNC(); MM(4, 0); PH_END();

    LDA4_1(0, 1);                     // ph7
    SB(T3, 1, 0);
    PH_SYNC(); MM(0, 4); PH_END();

    LDA4_1(4, 1);                     // ph8
    SB(T3, 1, 1);
    PH_SYNC(); MM(4, 4);
    VM4();                            // T2 fully landed

    // dribbled cvt stores after VM4 (become oldest vmem of next iter).
    if constexpr (CVTP > 0) {
#pragma unroll
      for (int p = 0; p < CVTP; ++p) {
        const size_t b8i = ((size_t)(j * CVTP + p) * ngrid + bid) * 512 + t;
        bf16x8 h;
        h[0] = (__bf16)cf[p][0].x; h[1] = (__bf16)cf[p][0].y;
        h[2] = (__bf16)cf[p][0].z; h[3] = (__bf16)cf[p][0].w;
        h[4] = (__bf16)cf[p][1].x; h[5] = (__bf16)cf[p][1].y;
        h[6] = (__bf16)cf[p][1].z; h[7] = (__bf16)cf[p][1].w;
        *(bf16x8*)((void*)(cvt_dst + b8i * 8)) = h;
      }
    }
    PH_END();
  }
  asm volatile("s_waitcnt vmcnt(0)" ::: "memory");

  // epilogue: D col = fr (N), row = hi*4 + jj (M)
  const int row0 = by * 256 + wm * 128 + hi * 4;
  const int col0 = bx * 256 + wn * 64 + fr;
#pragma unroll
  for (int n = 0; n < 4; ++n) {
    const int gc = col0 + n * 16;
    const float bv = bias[gc];
#pragma unroll
    for (int m = 0; m < 8; ++m) {
#pragma unroll
      for (int jj = 0; jj < 4; ++jj) {
        const size_t idx = (size_t)(row0 + m * 16 + jj) * NDIM + (size_t)gc;
        const float val = acc[m][n][jj] + bv;
        if constexpr (OUT_F32)
          ((float*)Cv)[idx] = val;
        else
          ((u16*)Cv)[idx] = __builtin_bit_cast(u16, (__bf16)val);
      }
    }
  }
}

// One wave per (b,l,h) attention unit: 8x8 scores over DK=64, softmax over e,
// PV, write x in-place over q (disjoint columns per head -> race-free).
__global__ __launch_bounds__(256) void attn_kernel(u16* __restrict__ qx,
                                                   const u16* __restrict__ kb,
                                                   const u16* __restrict__ vb) {
  __shared__ __align__(16) u16 qs[4][8][64];
  __shared__ __align__(16) u16 ks[4][8][64];
  __shared__ __align__(16) u16 vs[4][8][64];
  const int t = threadIdx.x;
  const int lane = t & 63;
  const int w = t >> 6;
  const int unit = blockIdx.x * 4 + w;
  const int bl = unit >> 4;
  const int h = unit & 15;
  const int row = lane >> 3;
  const int c8 = (lane & 7) * 8;
  const size_t goff = (size_t)bl * 8 * 1024 + (size_t)h * 64 + (size_t)row * 1024 + c8;

  *(int4*)((void*)&qs[w][row][c8]) = *(const int4*)((const void*)&qx[goff]);
  *(int4*)((void*)&ks[w][row][c8]) = *(const int4*)((const void*)&kb[goff]);
  *(int4*)((void*)&vs[w][row][c8]) = *(const int4*)((const void*)&vb[goff]);
  __syncthreads();

  const int a = row;
  const int e = lane & 7;
  float s = 0.f;
#pragma unroll
  for (int d8 = 0; d8 < 64; d8 += 8) {
    const bf16x8 qv = *(const bf16x8*)((const void*)&qs[w][a][d8]);
    const bf16x8 kv = *(const bf16x8*)((const void*)&ks[w][e][d8]);
#pragma unroll
    for (int j = 0; j < 8; ++j) s += (float)qv[j] * (float)kv[j];
  }
  s *= 0.125f;

  float mx = s;
#pragma unroll
  for (int o = 1; o < 8; o <<= 1) mx = fmaxf(mx, __shfl_xor(mx, o));
  float p = __expf(s - mx);
  float sum = p;
#pragma unroll
  for (int o = 1; o < 8; o <<= 1) sum += __shfl_xor(sum, o);
  p /= sum;

  float xo[8] = {};
#pragma unroll
  for (int e2 = 0; e2 < 8; ++e2) {
    const float pe = __shfl(p, (lane & 56) + e2);
    const bf16x8 vv = *(const bf16x8*)((const void*)&vs[w][e2][c8]);
#pragma unroll
    for (int j = 0; j < 8; ++j) xo[j] += pe * (float)vv[j];
  }
  bf16x8 hx;
#pragma unroll
  for (int j = 0; j < 8; ++j) hx[j] = (__bf16)xo[j];
  *(int4*)((void*)&qx[goff]) = __builtin_bit_cast(int4, hx);
}

extern "C" void kernel_launch(void* const* d_in, const int* in_sizes, int n_in,
                              void* d_out, int out_size, void* d_ws, size_t ws_size,
                              hipStream_t stream) {
  const float* query = (const float*)d_in[0];
  const float* key   = (const float*)d_in[1];
  const float* value = (const float*)d_in[2];
  const float* Wq = (const float*)d_in[3];
  const float* bq = (const float*)d_in[4];
  const float* Wk = (const float*)d_in[5];
  const float* bk = (const float*)d_in[6];
  const float* Wv = (const float*)d_in[7];
  const float* bv = (const float*)d_in[8];
  const float* Wo = (const float*)d_in[9];
  const float* bo = (const float*)d_in[10];
  (void)in_sizes; (void)n_in; (void)out_size; (void)ws_size;

  const size_t mn = (size_t)MROWS * (size_t)NDIM;

  // d_out temporarily holds kb+vb (bf16), dead before gemmo overwrites d_out
  // with fp32. ws: qb (67MB) | W bf16 x4 (8MB) | Abf (33.5MB).
  // Pipeline (each line: reads -> writes ; dribbled cvt):
  //   L1 cvtKW:    key_h1 -> qb_lo ; weights
  //   L2 gemmK_h1: qb_lo  -> kb_lo ; cvt key_h2   -> qb_hi
  //   L3 gemmK_h2: qb_hi  -> kb_hi ; cvt value_h1 -> Abf
  //   L4 gemmV_h1: Abf    -> vb_lo ; cvt value_h2 -> qb_lo   (key_h1 dead)
  //   L5 gemmV_h2: qb_lo  -> vb_hi ; cvt query_h1 -> qb_hi   (key_h2 dead)
  //   L6 gemmQ_h1: qb_hi  -> qb_lo ; cvt query_h2 -> Abf     (value_h1 dead)
  //   L7 gemmQ_h2: Abf    -> qb_hi
  //   L8 attn(qb, kb, vb) in-place x -> qb
  //   L9 gemmo:    qb -> d_out fp32
  u16* kb = (u16*)d_out;
  u16* vb = kb + mn;
  u16* qb = (u16*)d_ws;
  u16* Wqb = qb + mn;
  u16* Wkb = Wqb + 1048576;
  u16* Wvb = Wkb + 1048576;
  u16* Wob = Wvb + 1048576;
  u16* Abf = Wob + 1048576;
  u16* qb_hi = qb + MHALF;

  CvtArgs ca;
  ca.s[0] = Wq; ca.s[1] = Wk; ca.s[2] = Wv; ca.s[3] = Wo;
  ca.d[0] = Wqb; ca.d[1] = Wkb; ca.d[2] = Wvb; ca.d[3] = Wob;
  cvt_kw_kernel<<<10240, 256, 0, stream>>>(key, qb, ca);

  gemm8p<false, 2><<<256, 512, 0, stream>>>(qb, Wkb, bk, (void*)kb, 8,
                                            key + MHALF, qb_hi);
  gemm8p<false, 2><<<256, 512, 0, stream>>>(qb_hi, Wkb, bk, (void*)(kb + MHALF), 8,
                                            value, Abf);
  gemm8p<false, 2><<<256, 512, 0, stream>>>(Abf, Wvb, bv, (void*)vb, 8,
                                            value + MHALF, qb);
  gemm8p<false, 2><<<256, 512, 0, stream>>>(qb, Wvb, bv, (void*)(vb + MHALF), 8,
                                            query, qb_hi);
  gemm8p<false, 2><<<256, 512, 0, stream>>>(qb_hi, Wqb, bq, (void*)qb, 8,
                                            query + MHALF, Abf);
  gemm8p<false, 0><<<256, 512, 0, stream>>>(Abf, Wqb, bq, (void*)qb_hi, 8,
                                            nullptr, nullptr);

  attn_kernel<<<16384, 256, 0, stream>>>(qb, kb, vb);

  gemm8p<true, 0><<<512, 512, 0, stream>>>(qb, Wob, bo, d_out, 16,
                                           nullptr, nullptr);
}